// Round 11
// baseline (1456.202 us; speedup 1.0000x reference)
//
#include <hip/hip_runtime.h>
#include <cstdint>

#define N_ML 8   // MAX_LEN
#define HSTR 72  // h_lds row stride in bf16 elements

typedef __attribute__((ext_vector_type(8))) short bf16x8;
typedef __attribute__((ext_vector_type(4))) float f32x4;

__device__ __forceinline__ float fsigmoid(float x) { return 1.f / (1.f + __expf(-x)); }
__device__ __forceinline__ float ftanh_(float x) {
    float e = __expf(-2.f * fabsf(x));
    float t = (1.f - e) / (1.f + e);
    return x >= 0.f ? t : -t;
}
__device__ __forceinline__ float fselu(float x) {
    const float sc = 1.0507009873554805f, al = 1.6732632423543772f;
    return x > 0.f ? sc * x : sc * al * (__expf(x) - 1.f);
}
// f32 -> bf16 RTNE
__device__ __forceinline__ unsigned int f2bf(float f) {
    union { float f; unsigned int u; } v;
    v.f = f;
    unsigned int u = v.u;
    return (u + 0x7FFFu + ((u >> 16) & 1u)) >> 16;
}
__device__ __forceinline__ float bf2f(unsigned short u16) {
    union { unsigned int u; float f; } v;
    v.u = ((unsigned int)u16) << 16;
    return v.f;
}

// LDS-only barrier: waits DS ops, NOT vmcnt (no drain of prefetch/atomics).
__device__ __forceinline__ void barrier_lds_only() {
    asm volatile("s_waitcnt lgkmcnt(0)" ::: "memory");
    __builtin_amdgcn_s_barrier();
    asm volatile("" ::: "memory");
}

// ---- merged setup: prep_we | prep_ecc | init_states | build_idx | count ----
__global__ void __launch_bounds__(256)
setup_kernel(const float* __restrict__ ew1, const float* __restrict__ eb1,
             const float* __restrict__ ew2, const float* __restrict__ eb2,
             float* __restrict__ We, float* __restrict__ be,
             const float* __restrict__ wk, const float* __restrict__ bk,
             unsigned short* __restrict__ wkbf, unsigned short* __restrict__ bkbf,
             const float* __restrict__ li, const float* __restrict__ ni,
             const float* __restrict__ pi, float* __restrict__ ls,
             float* __restrict__ ns, float* __restrict__ ps,
             unsigned short* __restrict__ lsb16, unsigned short* __restrict__ nsb16,
             const int* __restrict__ paths, const int* __restrict__ seqs,
             const int* __restrict__ l2p, const int* __restrict__ n2p,
             unsigned int* __restrict__ gln, int* __restrict__ lens,
             const int* __restrict__ rcv, int* __restrict__ cnt,
             int n_links, int n_nodes, int n_paths, int E,
             int o_ecc, int o_init, int o_idx, int o_cnt) {
    const int b = blockIdx.x;
    const int tid = threadIdx.x;
    if (b < o_ecc) {
        int t = b * 256 + tid;
        if (t < 4096) {
            int k = t >> 5, j = t & 31;
            float a = 0.f;
            for (int i = 0; i < 32; ++i) a = fmaf(ew1[k * 32 + i], ew2[i * 32 + j], a);
            We[t] = a;
        }
        if (b == 0 && tid < 32) {
            int j = tid;
            float a = eb2[j];
            for (int i = 0; i < 32; ++i) a = fmaf(eb1[i], ew2[i * 32 + j], a);
            be[j] = a;
        }
    } else if (b < o_init) {
        int t = (b - o_ecc) * 256 + tid;
        if (t < 32768) {
            int o = t >> 10, q = t & 1023;
            int j = q >> 5, i = q & 31;
            wkbf[t] = (unsigned short)f2bf(wk[j * 1024 + i * 32 + o]);
        }
        if (t < 1024) {
            int o = t >> 5, i = t & 31;
            bkbf[t] = (unsigned short)f2bf(bk[i * 32 + o]);
        }
    } else if (b < o_idx) {
        int t = (b - o_init) * 256 + tid;
        float4 z = make_float4(0.f, 0.f, 0.f, 0.f);
        if (t < n_links) {
            float v = li[t];
            float4* r = (float4*)(ls + (size_t)t * 32);
            r[0] = make_float4(v, 0.f, 0.f, 0.f);
#pragma unroll
            for (int i = 1; i < 8; ++i) r[i] = z;
            uint4* bb = (uint4*)(lsb16 + (size_t)t * 32);
            uint4 zb = make_uint4(0, 0, 0, 0);
            bb[0] = make_uint4(f2bf(v), 0, 0, 0);
            bb[1] = zb; bb[2] = zb; bb[3] = zb;
        }
        if (t < n_nodes) {
            float v = ni[t];
            float4* r = (float4*)(ns + (size_t)t * 32);
            r[0] = make_float4(v, 0.f, 0.f, 0.f);
#pragma unroll
            for (int i = 1; i < 8; ++i) r[i] = z;
            uint4* bb = (uint4*)(nsb16 + (size_t)t * 32);
            uint4 zb = make_uint4(0, 0, 0, 0);
            bb[0] = make_uint4(f2bf(v), 0, 0, 0);
            bb[1] = zb; bb[2] = zb; bb[3] = zb;
        }
        if (t < n_paths) {
            float4* r = (float4*)(ps + (size_t)t * 64);
            r[0] = make_float4(pi[t], pi[n_paths + t], 0.f, 0.f);
#pragma unroll
            for (int i = 1; i < 16; ++i) r[i] = z;
        }
    } else if (b < o_cnt) {
        int e = (b - o_idx) * 256 + tid;
        if (e < E) {
            int p = paths[e], s = seqs[e];
            gln[(size_t)p * N_ML + s] =
                ((unsigned int)l2p[e] & 0xFFFFu) | ((unsigned int)n2p[e] << 16);
            atomicAdd(&lens[p], 1);
        }
    } else {
        int e = (b - o_cnt) * 256 + tid;
        if (e < n_links) atomicAdd(&cnt[rcv[e]], 1);
    }
}

__global__ void __launch_bounds__(1024, 1)
scan_kernel(const int* __restrict__ cnt, int* __restrict__ off, int n) {
    __shared__ int sd[1024];
    int tid = threadIdx.x;
    int chunk = (n + 1023) >> 10;
    int base = tid * chunk;
    int s = 0;
    for (int i = 0; i < chunk; ++i) {
        int idx = base + i;
        if (idx < n) s += cnt[idx];
    }
    sd[tid] = s;
    __syncthreads();
    for (int o = 1; o < 1024; o <<= 1) {
        int v = (tid >= o) ? sd[tid - o] : 0;
        __syncthreads();
        sd[tid] += v;
        __syncthreads();
    }
    int run = sd[tid] - s;  // exclusive
    for (int i = 0; i < chunk; ++i) {
        int idx = base + i;
        if (idx < n) {
            off[idx] = run;
            run += cnt[idx];
        }
    }
    if (tid == 1023) off[n] = sd[1023];
}

__global__ void scatter_kernel(const int* __restrict__ rcv, const int* __restrict__ off,
                               int* __restrict__ cur, int* __restrict__ csr_e, int E) {
    int e = blockIdx.x * 256 + threadIdx.x;
    if (e < E) {
        int l = rcv[e];
        int p = off[l] + atomicAdd(&cur[l], 1);
        csr_e[p] = e;
    }
}

// ---- GRU scan via MFMA; 256 thr / 4 waves / 32 paths per block ----
// High-TLP variant: ~20KB LDS, target 6-8 blocks/CU so many independent
// blocks' step-chains interleave. Wave wv = dim-block nw (16 dims each).
template <bool LAST>
__global__ void __launch_bounds__(256, 8)
gru_kernel(const unsigned short* __restrict__ lsb16, const unsigned short* __restrict__ nsb16,
           float* __restrict__ ps, float* __restrict__ m,
           const unsigned int* __restrict__ gln, const int* __restrict__ lens,
           const float* __restrict__ wx, const float* __restrict__ wh,
           const float* __restrict__ gb, int n_paths,
           const float* __restrict__ r_w1, const float* __restrict__ r_b1,
           const float* __restrict__ r_w2, const float* __restrict__ r_b2,
           const float* __restrict__ f_w, const float* __restrict__ f_b,
           float* __restrict__ out) {
    __shared__ unsigned short h_lds[2][32 * HSTR];  // 2 x 4.5KB
    __shared__ unsigned int gln_lds[N_ML * 32];     // 1KB  [t][row]
    __shared__ float h32[32 * 66];                  // 8.25KB final f32 h (LAST)
    __shared__ float r1_s[8][33];                   // 1KB readout stage (LAST)
    const int tid = threadIdx.x;
    const int lane = tid & 63;
    const int nw = tid >> 6;  // dim-block 0..3 (one wave each)
    const int l15 = lane & 15;
    const int kg = lane >> 4;  // 0..3
    const int pblk = blockIdx.x * 32;
    const int d = nw * 16 + l15;  // output dim 0..63

    {
        int st = tid >> 5, sr = tid & 31;  // 8 t-slots x 32 rows
        int pc = pblk + sr;
        gln_lds[st * 32 + sr] = (pc < n_paths) ? gln[(size_t)pc * N_ML + st] : 0xFFFFFFFFu;
    }

    bf16x8 Bz[4], Br[4], Bcx[2], Bch[2];
#pragma unroll
    for (int kt = 0; kt < 4; ++kt) {
        int kb = kt * 32 + kg * 8;
        const float* W = (kb < 64) ? (wx + (size_t)kb * 192) : (wh + (size_t)(kb - 64) * 192);
        bf16x8 vz, vr, vc;
#pragma unroll
        for (int j = 0; j < 8; ++j) {
            vz[j] = (short)f2bf(W[j * 192 + d]);
            vr[j] = (short)f2bf(W[j * 192 + 64 + d]);
            vc[j] = (short)f2bf(W[j * 192 + 128 + d]);
        }
        Bz[kt] = vz;
        Br[kt] = vr;
        if (kt < 2) Bcx[kt] = vc; else Bch[kt - 2] = vc;
    }
    const float bias_z = gb[d] + gb[192 + d];
    const float bias_r = gb[64 + d] + gb[192 + 64 + d];
    const float bias_xh = gb[128 + d];
    const float bias_hh = gb[192 + 128 + d];

    f32x4 hv[2];
    unsigned int plenp[2];
#pragma unroll
    for (int mt = 0; mt < 2; ++mt) {
        unsigned int pk = 0;
#pragma unroll
        for (int i = 0; i < 4; ++i) {
            int r = mt * 16 + kg * 4 + i;
            int pc = pblk + r;
            bool v = pc < n_paths;
            float h0 = v ? ps[(size_t)pc * 64 + d] : 0.f;
            hv[mt][i] = h0;
            pk |= (unsigned int)(v ? lens[pc] : 0) << (8 * i);
            h_lds[0][r * HSTR + d] = (unsigned short)f2bf(h0);
        }
        plenp[mt] = pk;
    }
    barrier_lds_only();

    bf16x8 ax0[2][2], ax1[2][2];  // [buf][mt]
    const bf16x8 zf = bf16x8{0, 0, 0, 0, 0, 0, 0, 0};

    auto loadx = [&](int t, int buf) {
#pragma unroll
        for (int mt = 0; mt < 2; ++mt) {
            int row = mt * 16 + l15;
            unsigned int g = gln_lds[t * 32 + row];
            ax0[buf][mt] = zf;
            ax1[buf][mt] = zf;
            if (g != 0xFFFFFFFFu) {
                int lk = (int)(g & 0xFFFFu);
                int nd = (int)(g >> 16);
                ax0[buf][mt] = *(const bf16x8*)(lsb16 + (size_t)lk * 32 + kg * 8);
                ax1[buf][mt] = *(const bf16x8*)(nsb16 + (size_t)nd * 32 + kg * 8);
            }
        }
    };
    loadx(0, 0);

#pragma unroll
    for (int t = 0; t < N_ML; ++t) {
        const int cb = t & 1, nb = cb ^ 1;
        if (t < N_ML - 1) loadx(t + 1, nb);
        bf16x8 ah0[2], ah1[2];
#pragma unroll
        for (int mt = 0; mt < 2; ++mt) {
            int row = mt * 16 + l15;
            ah0[mt] = *(const bf16x8*)(&h_lds[cb][row * HSTR + kg * 8]);
            ah1[mt] = *(const bf16x8*)(&h_lds[cb][row * HSTR + 32 + kg * 8]);
        }
        f32x4 accZ[2], accR[2], accXH[2], accHH[2];
#pragma unroll
        for (int mt = 0; mt < 2; ++mt) {
            accZ[mt] = f32x4{bias_z, bias_z, bias_z, bias_z};
            accR[mt] = f32x4{bias_r, bias_r, bias_r, bias_r};
            accXH[mt] = f32x4{bias_xh, bias_xh, bias_xh, bias_xh};
            accHH[mt] = f32x4{bias_hh, bias_hh, bias_hh, bias_hh};
            accZ[mt] = __builtin_amdgcn_mfma_f32_16x16x32_bf16(ax0[cb][mt], Bz[0], accZ[mt], 0, 0, 0);
            accZ[mt] = __builtin_amdgcn_mfma_f32_16x16x32_bf16(ax1[cb][mt], Bz[1], accZ[mt], 0, 0, 0);
            accZ[mt] = __builtin_amdgcn_mfma_f32_16x16x32_bf16(ah0[mt], Bz[2], accZ[mt], 0, 0, 0);
            accZ[mt] = __builtin_amdgcn_mfma_f32_16x16x32_bf16(ah1[mt], Bz[3], accZ[mt], 0, 0, 0);
            accR[mt] = __builtin_amdgcn_mfma_f32_16x16x32_bf16(ax0[cb][mt], Br[0], accR[mt], 0, 0, 0);
            accR[mt] = __builtin_amdgcn_mfma_f32_16x16x32_bf16(ax1[cb][mt], Br[1], accR[mt], 0, 0, 0);
            accR[mt] = __builtin_amdgcn_mfma_f32_16x16x32_bf16(ah0[mt], Br[2], accR[mt], 0, 0, 0);
            accR[mt] = __builtin_amdgcn_mfma_f32_16x16x32_bf16(ah1[mt], Br[3], accR[mt], 0, 0, 0);
            accXH[mt] = __builtin_amdgcn_mfma_f32_16x16x32_bf16(ax0[cb][mt], Bcx[0], accXH[mt], 0, 0, 0);
            accXH[mt] = __builtin_amdgcn_mfma_f32_16x16x32_bf16(ax1[cb][mt], Bcx[1], accXH[mt], 0, 0, 0);
            accHH[mt] = __builtin_amdgcn_mfma_f32_16x16x32_bf16(ah0[mt], Bch[0], accHH[mt], 0, 0, 0);
            accHH[mt] = __builtin_amdgcn_mfma_f32_16x16x32_bf16(ah1[mt], Bch[1], accHH[mt], 0, 0, 0);
        }
        float ov[2][4];
#pragma unroll
        for (int mt = 0; mt < 2; ++mt) {
#pragma unroll
            for (int i = 0; i < 4; ++i) {
                int r = mt * 16 + kg * 4 + i;
                float z = fsigmoid(accZ[mt][i]);
                float rr = fsigmoid(accR[mt][i]);
                float c = ftanh_(accXH[mt][i] + rr * accHH[mt][i]);
                float hn = z * hv[mt][i] + (1.f - z) * c;
                bool msk = ((plenp[mt] >> (8 * i)) & 0xFFu) > (unsigned int)t;
                float nh = msk ? hn : hv[mt][i];
                hv[mt][i] = nh;
                h_lds[nb][r * HSTR + d] = (unsigned short)f2bf(nh);
                ov[mt][i] = msk ? hn : 0.f;
            }
        }
        barrier_lds_only();  // LDS visibility only; vmcnt stays in flight
        if constexpr (!LAST) {
#pragma unroll
            for (int mt = 0; mt < 2; ++mt) {
#pragma unroll
                for (int i = 0; i < 4; ++i) {
                    int r = mt * 16 + kg * 4 + i;
                    unsigned int g = gln_lds[t * 32 + r];
                    if (g != 0xFFFFFFFFu)
                        atomicAdd(&m[(size_t)(g & 0xFFFFu) * 64 + d], ov[mt][i]);
                }
            }
        }
    }
    if constexpr (!LAST) {
#pragma unroll
        for (int mt = 0; mt < 2; ++mt) {
#pragma unroll
            for (int i = 0; i < 4; ++i) {
                int pc = pblk + mt * 16 + kg * 4 + i;
                if (pc < n_paths) ps[(size_t)pc * 64 + d] = hv[mt][i];
            }
        }
    } else {
        // fused readout: stage f32 h, then selu MLP + head per path
#pragma unroll
        for (int mt = 0; mt < 2; ++mt)
#pragma unroll
            for (int i = 0; i < 4; ++i) {
                int r = mt * 16 + kg * 4 + i;
                h32[r * 66 + d] = hv[mt][i];
            }
        barrier_lds_only();
        const int j = tid & 31, grp = tid >> 5;  // 8 groups of 32 lanes
#pragma unroll
        for (int pass = 0; pass < 4; ++pass) {
            int prow = pass * 8 + grp;
            int p = pblk + prow;
            float a = r_b1[j];
#pragma unroll 16
            for (int k = 0; k < 64; ++k) a = fmaf(h32[prow * 66 + k], r_w1[k * 32 + j], a);
            r1_s[grp][j] = fselu(a);
            barrier_lds_only();
            float bacc = r_b2[j];
#pragma unroll 8
            for (int k = 0; k < 32; ++k) bacc = fmaf(r1_s[grp][k], r_w2[k * 32 + j], bacc);
            float part = fselu(bacc) * f_w[j] + h32[prow * 66 + j] * f_w[32 + j] +
                         h32[prow * 66 + 32 + j] * f_w[64 + j];
#pragma unroll
            for (int o = 16; o > 0; o >>= 1) part += __shfl_down(part, o, 32);
            if (j == 0 && p < n_paths) out[p] = part + f_b[0];
            barrier_lds_only();
        }
    }
}

// ---- edge MLP (pre-folded): lsb16 = bf16(con @ We + be) ----
extern "C" __global__ void __launch_bounds__(256, 2)
edge_kernel(const float* __restrict__ ns, const float* __restrict__ lso,
            const float* __restrict__ m, const float* __restrict__ We,
            const float* __restrict__ be, const int* __restrict__ l2n,
            unsigned short* __restrict__ lsb16, int n_links) {
    __shared__ float We_l[4096];
    __shared__ float be_l[32];
    __shared__ float con_l[8][128];
    int tid = threadIdx.x;
    for (int i = tid; i < 4096; i += 256) We_l[i] = We[i];
    if (tid < 32) be_l[tid] = be[tid];
    int li = tid >> 5, o = tid & 31;
    int l = blockIdx.x * 8 + li;
    if (l < n_links) {
        con_l[li][o] = ns[(size_t)l2n[l] * 32 + o];
        con_l[li][32 + o] = lso[(size_t)l * 32 + o];
        con_l[li][64 + o] = m[(size_t)l * 64 + o];
        con_l[li][96 + o] = m[(size_t)l * 64 + 32 + o];
    }
    __syncthreads();
    if (l >= n_links) return;
    float acc = be_l[o];
#pragma unroll 8
    for (int k = 0; k < 128; ++k) acc = fmaf(con_l[li][k], We_l[k * 32 + o], acc);
    lsb16[(size_t)l * 32 + o] = (unsigned short)f2bf(acc);
}

// ---- ECCConv via MFMA bilinear form: msg = P @ wk_view + n @ bk_view ----
extern "C" __global__ void __launch_bounds__(256, 4)
ecc_kernel(const unsigned short* __restrict__ lsb16, const unsigned short* __restrict__ nsb16,
           const unsigned short* __restrict__ wkbf, const unsigned short* __restrict__ bkbf,
           const int* __restrict__ senders, float* __restrict__ msg, int n_links) {
    __shared__ float part[4][64 * 32];  // [wave][row][o] f32, 32KB
    const int tid = threadIdx.x;
    const int lane = tid & 63;
    const int wv = tid >> 6;   // K-slice 0..3
    const int l15 = lane & 15;
    const int kg = lane >> 4;  // 0..3
    const int lblk = blockIdx.x * 64;
    const bf16x8 zf = bf16x8{0, 0, 0, 0, 0, 0, 0, 0};

    bf16x8 Bf[8][2], Bb[2];
#pragma unroll
    for (int kt = 0; kt < 8; ++kt) {
#pragma unroll
        for (int nb = 0; nb < 2; ++nb) {
            int o = nb * 16 + l15;
            Bf[kt][nb] = *(const bf16x8*)(wkbf + (size_t)o * 1024 + wv * 256 + kt * 32 + kg * 8);
        }
    }
#pragma unroll
    for (int nb = 0; nb < 2; ++nb) {
        int o = nb * 16 + l15;
        Bb[nb] = *(const bf16x8*)(bkbf + (size_t)o * 32 + kg * 8);
    }

    f32x4 acc[4][2];
#pragma unroll
    for (int mt = 0; mt < 4; ++mt)
#pragma unroll
        for (int nb = 0; nb < 2; ++nb) acc[mt][nb] = f32x4{0.f, 0.f, 0.f, 0.f};

#pragma unroll
    for (int mt = 0; mt < 4; ++mt) {
        int link = lblk + mt * 16 + l15;
        bool ok = link < n_links;
        bf16x8 nv8 = zf, lsv8 = zf;
        if (ok) {
            int snd = senders[link];
            nv8 = *(const bf16x8*)(nsb16 + (size_t)snd * 32 + kg * 8);
            lsv8 = *(const bf16x8*)(lsb16 + (size_t)link * 32 + wv * 8);
        }
        float nf[8], lf[8];
#pragma unroll
        for (int j = 0; j < 8; ++j) {
            nf[j] = bf2f((unsigned short)nv8[j]);
            lf[j] = bf2f((unsigned short)lsv8[j]);
        }
#pragma unroll
        for (int kt = 0; kt < 8; ++kt) {
            bf16x8 aA;
#pragma unroll
            for (int jj = 0; jj < 8; ++jj) aA[jj] = (short)f2bf(lf[kt] * nf[jj]);
            acc[mt][0] = __builtin_amdgcn_mfma_f32_16x16x32_bf16(aA, Bf[kt][0], acc[mt][0], 0, 0, 0);
            acc[mt][1] = __builtin_amdgcn_mfma_f32_16x16x32_bf16(aA, Bf[kt][1], acc[mt][1], 0, 0, 0);
        }
        if (wv == 0) {
            acc[mt][0] = __builtin_amdgcn_mfma_f32_16x16x32_bf16(nv8, Bb[0], acc[mt][0], 0, 0, 0);
            acc[mt][1] = __builtin_amdgcn_mfma_f32_16x16x32_bf16(nv8, Bb[1], acc[mt][1], 0, 0, 0);
        }
    }
#pragma unroll
    for (int mt = 0; mt < 4; ++mt)
#pragma unroll
        for (int nb = 0; nb < 2; ++nb)
#pragma unroll
            for (int i = 0; i < 4; ++i)
                part[wv][(mt * 16 + kg * 4 + i) * 32 + nb * 16 + l15] = acc[mt][nb][i];
    __syncthreads();
    {
        int f = tid * 8;
        int link = lblk + (f >> 5);
        if (link < n_links) {
            float4 s0 = make_float4(0.f, 0.f, 0.f, 0.f), s1 = s0;
#pragma unroll
            for (int w = 0; w < 4; ++w) {
                const float4* p = (const float4*)(&part[w][f]);
                float4 a = p[0], b = p[1];
                s0.x += a.x; s0.y += a.y; s0.z += a.z; s0.w += a.w;
                s1.x += b.x; s1.y += b.y; s1.z += b.z; s1.w += b.w;
            }
            float4* dst = (float4*)(msg + (size_t)link * 32 + (f & 31));
            dst[0] = s0;
            dst[1] = s1;
        }
    }
}

// ---- node update: nsb16 = bf16(CSR-gather(msg) + ns_old @ wroot + broot) ----
extern "C" __global__ void __launch_bounds__(256, 2)
node_kernel(const float* __restrict__ msg, const int* __restrict__ csr_off,
            const int* __restrict__ csr_e, const float* __restrict__ nso,
            const float* __restrict__ wroot, const float* __restrict__ broot,
            unsigned short* __restrict__ nsb16, int n_nodes) {
    __shared__ float wr_l[1024];
    __shared__ float ns_s[8][32];
    int tid = threadIdx.x;
    for (int i = tid; i < 1024; i += 256) wr_l[i] = wroot[i];
    int ni = tid >> 5, o = tid & 31;
    int n = blockIdx.x * 8 + ni;
    if (n < n_nodes) ns_s[ni][o] = nso[(size_t)n * 32 + o];
    __syncthreads();
    if (n >= n_nodes) return;
    float acc = broot[o];
    {
        int k = csr_off[n], kend = csr_off[n + 1];
        for (; k + 2 <= kend; k += 2) {
            int e0 = csr_e[k], e1 = csr_e[k + 1];
            acc += msg[(size_t)e0 * 32 + o] + msg[(size_t)e1 * 32 + o];
        }
        if (k < kend) acc += msg[(size_t)csr_e[k] * 32 + o];
    }
#pragma unroll 8
    for (int k = 0; k < 32; ++k) acc = fmaf(ns_s[ni][k], wr_l[k * 32 + o], acc);
    nsb16[(size_t)n * 32 + o] = (unsigned short)f2bf(acc);
}

extern "C" void kernel_launch(void* const* d_in, const int* in_sizes, int n_in,
                              void* d_out, int out_size, void* d_ws, size_t ws_size,
                              hipStream_t stream) {
    const float* link_init = (const float*)d_in[0];
    const float* node_init = (const float*)d_in[1];
    const float* path_init = (const float*)d_in[2];
    const float* gru_wx = (const float*)d_in[3];
    const float* gru_wh = (const float*)d_in[4];
    const float* gru_b = (const float*)d_in[5];
    const float* e_w1 = (const float*)d_in[6];
    const float* e_b1 = (const float*)d_in[7];
    const float* e_w2 = (const float*)d_in[8];
    const float* e_b2 = (const float*)d_in[9];
    const float* ecc_wk = (const float*)d_in[10];
    const float* ecc_bk = (const float*)d_in[11];
    const float* ecc_wroot = (const float*)d_in[12];
    const float* ecc_broot = (const float*)d_in[13];
    const float* r_w1 = (const float*)d_in[14];
    const float* r_b1 = (const float*)d_in[15];
    const float* r_w2 = (const float*)d_in[16];
    const float* r_b2 = (const float*)d_in[17];
    const float* f_w = (const float*)d_in[18];
    const float* f_b = (const float*)d_in[19];
    const int* p2l = (const int*)d_in[20];
    const int* sseq = (const int*)d_in[21];
    const int* l2p = (const int*)d_in[22];
    const int* n2p = (const int*)d_in[23];
    const int* l2n = (const int*)d_in[24];
    const int* senders = (const int*)d_in[25];
    const int* receivers = (const int*)d_in[26];

    const int nl = in_sizes[0];
    const int nn = in_sizes[1];
    const int np = in_sizes[2] / 2;
    const int E = in_sizes[20];

    char* base = (char*)d_ws;
    size_t off = 0;
    auto give = [&](size_t nbytes) -> void* {
        void* p = base + off;
        off += (nbytes + 255) & ~(size_t)255;
        return p;
    };
    float* ls0 = (float*)give((size_t)nl * 32 * 4);
    float* ns0 = (float*)give((size_t)nn * 32 * 4);
    float* ps = (float*)give((size_t)np * 64 * 4);
    float* We = (float*)give(4096 * 4);
    float* be = (float*)give(32 * 4);
    unsigned int* gln = (unsigned int*)give((size_t)np * N_ML * 4);
    unsigned short* lsb16 = (unsigned short*)give((size_t)nl * 32 * 2);
    unsigned short* nsb16 = (unsigned short*)give((size_t)nn * 32 * 2);
    unsigned short* wkbf = (unsigned short*)give(32768 * 2);
    unsigned short* bkbf = (unsigned short*)give(1024 * 2);
    float* msg = (float*)give((size_t)nl * 32 * 4);
    int* csr_off = (int*)give((size_t)(nn + 1) * 4);
    int* csr_e = (int*)give((size_t)nl * 4);
    // contiguous zero region: lensb | cntn | curn | m  (single memset)
    char* zbase = base + off;
    int* lensb = (int*)give((size_t)np * 4);
    int* cntn = (int*)give((size_t)nn * 4);
    int* curn = (int*)give((size_t)nn * 4);
    float* m = (float*)give((size_t)nl * 64 * 4);
    size_t zlen = (char*)(m + (size_t)nl * 64) - zbase;

    hipMemsetAsync(zbase, 0, zlen, stream);
    hipMemsetAsync(gln, 0xFF, (size_t)np * N_ML * 4, stream);

    // merged setup dispatch
    const int nb_init = (((nl > nn ? nl : nn) > np ? (nl > nn ? nl : nn) : np) + 255) / 256;
    const int nb_idx = (E + 255) / 256;
    const int nb_cnt = (nl + 255) / 256;
    const int o_ecc = 16;
    const int o_init = o_ecc + 128;
    const int o_idx = o_init + nb_init;
    const int o_cnt = o_idx + nb_idx;
    const int nb_tot = o_cnt + nb_cnt;
    setup_kernel<<<nb_tot, 256, 0, stream>>>(
        e_w1, e_b1, e_w2, e_b2, We, be, ecc_wk, ecc_bk, wkbf, bkbf,
        link_init, node_init, path_init, ls0, ns0, ps, lsb16, nsb16,
        p2l, sseq, l2p, n2p, gln, lensb, receivers, cntn,
        nl, nn, np, E, o_ecc, o_init, o_idx, o_cnt);
    scan_kernel<<<1, 1024, 0, stream>>>(cntn, csr_off, nn);
    scatter_kernel<<<(nl + 255) / 256, 256, 0, stream>>>(receivers, csr_off, curn, csr_e, nl);

    const int gblocks = (np + 31) / 32;
    // iter 1: full update
    gru_kernel<false><<<gblocks, 256, 0, stream>>>(
        lsb16, nsb16, ps, m, gln, lensb, gru_wx, gru_wh, gru_b, np,
        r_w1, r_b1, r_w2, r_b2, f_w, f_b, (float*)d_out);
    edge_kernel<<<(nl + 7) / 8, 256, 0, stream>>>(ns0, ls0, m, We, be, l2n, lsb16, nl);
    ecc_kernel<<<(nl + 63) / 64, 256, 0, stream>>>(lsb16, nsb16, wkbf, bkbf, senders, msg, nl);
    node_kernel<<<(nn + 7) / 8, 256, 0, stream>>>(msg, csr_off, csr_e, ns0, ecc_wroot,
                                                  ecc_broot, nsb16, nn);
    // iter 2: only path_state matters -> gru with fused readout
    gru_kernel<true><<<gblocks, 256, 0, stream>>>(
        lsb16, nsb16, ps, m, gln, lensb, gru_wx, gru_wh, gru_b, np,
        r_w1, r_b1, r_w2, r_b2, f_w, f_b, (float*)d_out);
}

// Round 12
// 765.794 us; speedup vs baseline: 1.9016x; 1.9016x over previous
//
#include <hip/hip_runtime.h>
#include <cstdint>

#define N_ML 8   // MAX_LEN
#define HSTR 72  // h_lds row stride in bf16 elements

typedef __attribute__((ext_vector_type(8))) short bf16x8;
typedef __attribute__((ext_vector_type(4))) float f32x4;

__device__ __forceinline__ float fsigmoid(float x) { return 1.f / (1.f + __expf(-x)); }
// tanh(x) = 2*sigmoid(2x) - 1  (exact, saturates correctly at +/-inf)
__device__ __forceinline__ float ftanh_(float x) {
    return fmaf(2.f, 1.f / (1.f + __expf(-2.f * x)), -1.f);
}
__device__ __forceinline__ float fselu(float x) {
    const float sc = 1.0507009873554805f, al = 1.6732632423543772f;
    return x > 0.f ? sc * x : sc * al * (__expf(x) - 1.f);
}
// f32 -> bf16 RTNE
__device__ __forceinline__ unsigned int f2bf(float f) {
    union { float f; unsigned int u; } v;
    v.f = f;
    unsigned int u = v.u;
    return (u + 0x7FFFu + ((u >> 16) & 1u)) >> 16;
}
__device__ __forceinline__ float bf2f(unsigned short u16) {
    union { unsigned int u; float f; } v;
    v.u = ((unsigned int)u16) << 16;
    return v.f;
}

// LDS-only barrier: waits DS ops, NOT vmcnt (no drain of prefetch/atomics).
__device__ __forceinline__ void barrier_lds_only() {
    asm volatile("s_waitcnt lgkmcnt(0)" ::: "memory");
    __builtin_amdgcn_s_barrier();
    asm volatile("" ::: "memory");
}

// ---- merged setup: prep_we | prep_ecc | init_states | build_idx | count ----
__global__ void __launch_bounds__(256)
setup_kernel(const float* __restrict__ ew1, const float* __restrict__ eb1,
             const float* __restrict__ ew2, const float* __restrict__ eb2,
             float* __restrict__ We, float* __restrict__ be,
             const float* __restrict__ wk, const float* __restrict__ bk,
             unsigned short* __restrict__ wkbf, unsigned short* __restrict__ bkbf,
             const float* __restrict__ li, const float* __restrict__ ni,
             const float* __restrict__ pi, float* __restrict__ ls,
             float* __restrict__ ns, float* __restrict__ ps,
             unsigned short* __restrict__ lsb16, unsigned short* __restrict__ nsb16,
             const int* __restrict__ paths, const int* __restrict__ seqs,
             const int* __restrict__ l2p, const int* __restrict__ n2p,
             unsigned int* __restrict__ gln, int* __restrict__ lens,
             const int* __restrict__ rcv, int* __restrict__ cnt,
             int n_links, int n_nodes, int n_paths, int E,
             int o_ecc, int o_init, int o_idx, int o_cnt) {
    const int b = blockIdx.x;
    const int tid = threadIdx.x;
    if (b < o_ecc) {
        int t = b * 256 + tid;
        if (t < 4096) {
            int k = t >> 5, j = t & 31;
            float a = 0.f;
            for (int i = 0; i < 32; ++i) a = fmaf(ew1[k * 32 + i], ew2[i * 32 + j], a);
            We[t] = a;
        }
        if (b == 0 && tid < 32) {
            int j = tid;
            float a = eb2[j];
            for (int i = 0; i < 32; ++i) a = fmaf(eb1[i], ew2[i * 32 + j], a);
            be[j] = a;
        }
    } else if (b < o_init) {
        int t = (b - o_ecc) * 256 + tid;
        if (t < 32768) {
            int o = t >> 10, q = t & 1023;
            int j = q >> 5, i = q & 31;
            wkbf[t] = (unsigned short)f2bf(wk[j * 1024 + i * 32 + o]);
        }
        if (t < 1024) {
            int o = t >> 5, i = t & 31;
            bkbf[t] = (unsigned short)f2bf(bk[i * 32 + o]);
        }
    } else if (b < o_idx) {
        int t = (b - o_init) * 256 + tid;
        float4 z = make_float4(0.f, 0.f, 0.f, 0.f);
        if (t < n_links) {
            float v = li[t];
            float4* r = (float4*)(ls + (size_t)t * 32);
            r[0] = make_float4(v, 0.f, 0.f, 0.f);
#pragma unroll
            for (int i = 1; i < 8; ++i) r[i] = z;
            uint4* bb = (uint4*)(lsb16 + (size_t)t * 32);
            uint4 zb = make_uint4(0, 0, 0, 0);
            bb[0] = make_uint4(f2bf(v), 0, 0, 0);
            bb[1] = zb; bb[2] = zb; bb[3] = zb;
        }
        if (t < n_nodes) {
            float v = ni[t];
            float4* r = (float4*)(ns + (size_t)t * 32);
            r[0] = make_float4(v, 0.f, 0.f, 0.f);
#pragma unroll
            for (int i = 1; i < 8; ++i) r[i] = z;
            uint4* bb = (uint4*)(nsb16 + (size_t)t * 32);
            uint4 zb = make_uint4(0, 0, 0, 0);
            bb[0] = make_uint4(f2bf(v), 0, 0, 0);
            bb[1] = zb; bb[2] = zb; bb[3] = zb;
        }
        if (t < n_paths) {
            float4* r = (float4*)(ps + (size_t)t * 64);
            r[0] = make_float4(pi[t], pi[n_paths + t], 0.f, 0.f);
#pragma unroll
            for (int i = 1; i < 16; ++i) r[i] = z;
        }
    } else if (b < o_cnt) {
        int e = (b - o_idx) * 256 + tid;
        if (e < E) {
            int p = paths[e], s = seqs[e];
            gln[(size_t)p * N_ML + s] =
                ((unsigned int)l2p[e] & 0xFFFFu) | ((unsigned int)n2p[e] << 16);
            atomicAdd(&lens[p], 1);
        }
    } else {
        int e = (b - o_cnt) * 256 + tid;
        if (e < n_links) atomicAdd(&cnt[rcv[e]], 1);
    }
}

__global__ void __launch_bounds__(1024, 1)
scan_kernel(const int* __restrict__ cnt, int* __restrict__ off, int n) {
    __shared__ int sd[1024];
    int tid = threadIdx.x;
    int chunk = (n + 1023) >> 10;
    int base = tid * chunk;
    int s = 0;
    for (int i = 0; i < chunk; ++i) {
        int idx = base + i;
        if (idx < n) s += cnt[idx];
    }
    sd[tid] = s;
    __syncthreads();
    for (int o = 1; o < 1024; o <<= 1) {
        int v = (tid >= o) ? sd[tid - o] : 0;
        __syncthreads();
        sd[tid] += v;
        __syncthreads();
    }
    int run = sd[tid] - s;  // exclusive
    for (int i = 0; i < chunk; ++i) {
        int idx = base + i;
        if (idx < n) {
            off[idx] = run;
            run += cnt[idx];
        }
    }
    if (tid == 1023) off[n] = sd[1023];
}

__global__ void scatter_kernel(const int* __restrict__ rcv, const int* __restrict__ off,
                               int* __restrict__ cur, int* __restrict__ csr_e, int E) {
    int e = blockIdx.x * 256 + threadIdx.x;
    if (e < E) {
        int l = rcv[e];
        int p = off[l] + atomicAdd(&cur[l], 1);
        csr_e[p] = e;
    }
}

// ---- GRU scan via MFMA; 256 thr / 4 waves / 32 paths per block ----
// High-TLP variant with VGPR cap 128 (NOT 32 — R11's (256,8) bound caused
// weight rematerialization from global, FETCH 14MB->936MB).
template <bool LAST>
__global__ void __launch_bounds__(256, 4)
gru_kernel(const unsigned short* __restrict__ lsb16, const unsigned short* __restrict__ nsb16,
           float* __restrict__ ps, float* __restrict__ m,
           const unsigned int* __restrict__ gln, const int* __restrict__ lens,
           const float* __restrict__ wx, const float* __restrict__ wh,
           const float* __restrict__ gb, int n_paths,
           const float* __restrict__ r_w1, const float* __restrict__ r_b1,
           const float* __restrict__ r_w2, const float* __restrict__ r_b2,
           const float* __restrict__ f_w, const float* __restrict__ f_b,
           float* __restrict__ out) {
    __shared__ unsigned short h_lds[2][32 * HSTR];  // 2 x 4.5KB
    __shared__ unsigned int gln_lds[N_ML * 32];     // 1KB  [t][row]
    __shared__ float h32[32 * 66];                  // 8.25KB final f32 h (LAST)
    __shared__ float r1_s[8][33];                   // 1KB readout stage (LAST)
    const int tid = threadIdx.x;
    const int lane = tid & 63;
    const int nw = tid >> 6;  // dim-block 0..3 (one wave each)
    const int l15 = lane & 15;
    const int kg = lane >> 4;  // 0..3
    const int pblk = blockIdx.x * 32;
    const int d = nw * 16 + l15;  // output dim 0..63

    {
        int st = tid >> 5, sr = tid & 31;  // 8 t-slots x 32 rows
        int pc = pblk + sr;
        gln_lds[st * 32 + sr] = (pc < n_paths) ? gln[(size_t)pc * N_ML + st] : 0xFFFFFFFFu;
    }

    bf16x8 Bz[4], Br[4], Bcx[2], Bch[2];
#pragma unroll
    for (int kt = 0; kt < 4; ++kt) {
        int kb = kt * 32 + kg * 8;
        const float* W = (kb < 64) ? (wx + (size_t)kb * 192) : (wh + (size_t)(kb - 64) * 192);
        bf16x8 vz, vr, vc;
#pragma unroll
        for (int j = 0; j < 8; ++j) {
            vz[j] = (short)f2bf(W[j * 192 + d]);
            vr[j] = (short)f2bf(W[j * 192 + 64 + d]);
            vc[j] = (short)f2bf(W[j * 192 + 128 + d]);
        }
        Bz[kt] = vz;
        Br[kt] = vr;
        if (kt < 2) Bcx[kt] = vc; else Bch[kt - 2] = vc;
    }
    const float bias_z = gb[d] + gb[192 + d];
    const float bias_r = gb[64 + d] + gb[192 + 64 + d];
    const float bias_xh = gb[128 + d];
    const float bias_hh = gb[192 + 128 + d];

    f32x4 hv[2];
    unsigned int plenp[2];
#pragma unroll
    for (int mt = 0; mt < 2; ++mt) {
        unsigned int pk = 0;
#pragma unroll
        for (int i = 0; i < 4; ++i) {
            int r = mt * 16 + kg * 4 + i;
            int pc = pblk + r;
            bool v = pc < n_paths;
            float h0 = v ? ps[(size_t)pc * 64 + d] : 0.f;
            hv[mt][i] = h0;
            pk |= (unsigned int)(v ? lens[pc] : 0) << (8 * i);
            h_lds[0][r * HSTR + d] = (unsigned short)f2bf(h0);
        }
        plenp[mt] = pk;
    }
    barrier_lds_only();

    bf16x8 ax0[2][2], ax1[2][2];  // [buf][mt]
    const bf16x8 zf = bf16x8{0, 0, 0, 0, 0, 0, 0, 0};

    auto loadx = [&](int t, int buf) {
#pragma unroll
        for (int mt = 0; mt < 2; ++mt) {
            int row = mt * 16 + l15;
            unsigned int g = gln_lds[t * 32 + row];
            ax0[buf][mt] = zf;
            ax1[buf][mt] = zf;
            if (g != 0xFFFFFFFFu) {
                int lk = (int)(g & 0xFFFFu);
                int nd = (int)(g >> 16);
                ax0[buf][mt] = *(const bf16x8*)(lsb16 + (size_t)lk * 32 + kg * 8);
                ax1[buf][mt] = *(const bf16x8*)(nsb16 + (size_t)nd * 32 + kg * 8);
            }
        }
    };
    loadx(0, 0);

#pragma unroll
    for (int t = 0; t < N_ML; ++t) {
        const int cb = t & 1, nb = cb ^ 1;
        if (t < N_ML - 1) loadx(t + 1, nb);
        bf16x8 ah0[2], ah1[2];
#pragma unroll
        for (int mt = 0; mt < 2; ++mt) {
            int row = mt * 16 + l15;
            ah0[mt] = *(const bf16x8*)(&h_lds[cb][row * HSTR + kg * 8]);
            ah1[mt] = *(const bf16x8*)(&h_lds[cb][row * HSTR + 32 + kg * 8]);
        }
        f32x4 accZ[2], accR[2], accXH[2], accHH[2];
#pragma unroll
        for (int mt = 0; mt < 2; ++mt) {
            accZ[mt] = f32x4{bias_z, bias_z, bias_z, bias_z};
            accR[mt] = f32x4{bias_r, bias_r, bias_r, bias_r};
            accXH[mt] = f32x4{bias_xh, bias_xh, bias_xh, bias_xh};
            accHH[mt] = f32x4{bias_hh, bias_hh, bias_hh, bias_hh};
            accZ[mt] = __builtin_amdgcn_mfma_f32_16x16x32_bf16(ax0[cb][mt], Bz[0], accZ[mt], 0, 0, 0);
            accZ[mt] = __builtin_amdgcn_mfma_f32_16x16x32_bf16(ax1[cb][mt], Bz[1], accZ[mt], 0, 0, 0);
            accZ[mt] = __builtin_amdgcn_mfma_f32_16x16x32_bf16(ah0[mt], Bz[2], accZ[mt], 0, 0, 0);
            accZ[mt] = __builtin_amdgcn_mfma_f32_16x16x32_bf16(ah1[mt], Bz[3], accZ[mt], 0, 0, 0);
            accR[mt] = __builtin_amdgcn_mfma_f32_16x16x32_bf16(ax0[cb][mt], Br[0], accR[mt], 0, 0, 0);
            accR[mt] = __builtin_amdgcn_mfma_f32_16x16x32_bf16(ax1[cb][mt], Br[1], accR[mt], 0, 0, 0);
            accR[mt] = __builtin_amdgcn_mfma_f32_16x16x32_bf16(ah0[mt], Br[2], accR[mt], 0, 0, 0);
            accR[mt] = __builtin_amdgcn_mfma_f32_16x16x32_bf16(ah1[mt], Br[3], accR[mt], 0, 0, 0);
            accXH[mt] = __builtin_amdgcn_mfma_f32_16x16x32_bf16(ax0[cb][mt], Bcx[0], accXH[mt], 0, 0, 0);
            accXH[mt] = __builtin_amdgcn_mfma_f32_16x16x32_bf16(ax1[cb][mt], Bcx[1], accXH[mt], 0, 0, 0);
            accHH[mt] = __builtin_amdgcn_mfma_f32_16x16x32_bf16(ah0[mt], Bch[0], accHH[mt], 0, 0, 0);
            accHH[mt] = __builtin_amdgcn_mfma_f32_16x16x32_bf16(ah1[mt], Bch[1], accHH[mt], 0, 0, 0);
        }
        float ov[2][4];
#pragma unroll
        for (int mt = 0; mt < 2; ++mt) {
#pragma unroll
            for (int i = 0; i < 4; ++i) {
                int r = mt * 16 + kg * 4 + i;
                float z = fsigmoid(accZ[mt][i]);
                float rr = fsigmoid(accR[mt][i]);
                float c = ftanh_(accXH[mt][i] + rr * accHH[mt][i]);
                float hn = z * hv[mt][i] + (1.f - z) * c;
                bool msk = ((plenp[mt] >> (8 * i)) & 0xFFu) > (unsigned int)t;
                float nh = msk ? hn : hv[mt][i];
                hv[mt][i] = nh;
                h_lds[nb][r * HSTR + d] = (unsigned short)f2bf(nh);
                ov[mt][i] = msk ? hn : 0.f;
            }
        }
        barrier_lds_only();  // LDS visibility only; vmcnt stays in flight
        if constexpr (!LAST) {
#pragma unroll
            for (int mt = 0; mt < 2; ++mt) {
#pragma unroll
                for (int i = 0; i < 4; ++i) {
                    int r = mt * 16 + kg * 4 + i;
                    unsigned int g = gln_lds[t * 32 + r];
                    if (g != 0xFFFFFFFFu)
                        atomicAdd(&m[(size_t)(g & 0xFFFFu) * 64 + d], ov[mt][i]);
                }
            }
        }
    }
    if constexpr (!LAST) {
#pragma unroll
        for (int mt = 0; mt < 2; ++mt) {
#pragma unroll
            for (int i = 0; i < 4; ++i) {
                int pc = pblk + mt * 16 + kg * 4 + i;
                if (pc < n_paths) ps[(size_t)pc * 64 + d] = hv[mt][i];
            }
        }
    } else {
        // fused readout: stage f32 h, then selu MLP + head per path
#pragma unroll
        for (int mt = 0; mt < 2; ++mt)
#pragma unroll
            for (int i = 0; i < 4; ++i) {
                int r = mt * 16 + kg * 4 + i;
                h32[r * 66 + d] = hv[mt][i];
            }
        barrier_lds_only();
        const int j = tid & 31, grp = tid >> 5;  // 8 groups of 32 lanes
#pragma unroll
        for (int pass = 0; pass < 4; ++pass) {
            int prow = pass * 8 + grp;
            int p = pblk + prow;
            float a = r_b1[j];
#pragma unroll 16
            for (int k = 0; k < 64; ++k) a = fmaf(h32[prow * 66 + k], r_w1[k * 32 + j], a);
            r1_s[grp][j] = fselu(a);
            barrier_lds_only();
            float bacc = r_b2[j];
#pragma unroll 8
            for (int k = 0; k < 32; ++k) bacc = fmaf(r1_s[grp][k], r_w2[k * 32 + j], bacc);
            float part = fselu(bacc) * f_w[j] + h32[prow * 66 + j] * f_w[32 + j] +
                         h32[prow * 66 + 32 + j] * f_w[64 + j];
#pragma unroll
            for (int o = 16; o > 0; o >>= 1) part += __shfl_down(part, o, 32);
            if (j == 0 && p < n_paths) out[p] = part + f_b[0];
            barrier_lds_only();
        }
    }
}

// ---- edge MLP (pre-folded): lsb16 = bf16(con @ We + be) ----
extern "C" __global__ void __launch_bounds__(256, 2)
edge_kernel(const float* __restrict__ ns, const float* __restrict__ lso,
            const float* __restrict__ m, const float* __restrict__ We,
            const float* __restrict__ be, const int* __restrict__ l2n,
            unsigned short* __restrict__ lsb16, int n_links) {
    __shared__ float We_l[4096];
    __shared__ float be_l[32];
    __shared__ float con_l[8][128];
    int tid = threadIdx.x;
    for (int i = tid; i < 4096; i += 256) We_l[i] = We[i];
    if (tid < 32) be_l[tid] = be[tid];
    int li = tid >> 5, o = tid & 31;
    int l = blockIdx.x * 8 + li;
    if (l < n_links) {
        con_l[li][o] = ns[(size_t)l2n[l] * 32 + o];
        con_l[li][32 + o] = lso[(size_t)l * 32 + o];
        con_l[li][64 + o] = m[(size_t)l * 64 + o];
        con_l[li][96 + o] = m[(size_t)l * 64 + 32 + o];
    }
    __syncthreads();
    if (l >= n_links) return;
    float acc = be_l[o];
#pragma unroll 8
    for (int k = 0; k < 128; ++k) acc = fmaf(con_l[li][k], We_l[k * 32 + o], acc);
    lsb16[(size_t)l * 32 + o] = (unsigned short)f2bf(acc);
}

// ---- ECCConv via MFMA bilinear form: msg = P @ wk_view + n @ bk_view ----
extern "C" __global__ void __launch_bounds__(256, 4)
ecc_kernel(const unsigned short* __restrict__ lsb16, const unsigned short* __restrict__ nsb16,
           const unsigned short* __restrict__ wkbf, const unsigned short* __restrict__ bkbf,
           const int* __restrict__ senders, float* __restrict__ msg, int n_links) {
    __shared__ float part[4][64 * 32];  // [wave][row][o] f32, 32KB
    const int tid = threadIdx.x;
    const int lane = tid & 63;
    const int wv = tid >> 6;   // K-slice 0..3
    const int l15 = lane & 15;
    const int kg = lane >> 4;  // 0..3
    const int lblk = blockIdx.x * 64;
    const bf16x8 zf = bf16x8{0, 0, 0, 0, 0, 0, 0, 0};

    bf16x8 Bf[8][2], Bb[2];
#pragma unroll
    for (int kt = 0; kt < 8; ++kt) {
#pragma unroll
        for (int nb = 0; nb < 2; ++nb) {
            int o = nb * 16 + l15;
            Bf[kt][nb] = *(const bf16x8*)(wkbf + (size_t)o * 1024 + wv * 256 + kt * 32 + kg * 8);
        }
    }
#pragma unroll
    for (int nb = 0; nb < 2; ++nb) {
        int o = nb * 16 + l15;
        Bb[nb] = *(const bf16x8*)(bkbf + (size_t)o * 32 + kg * 8);
    }

    f32x4 acc[4][2];
#pragma unroll
    for (int mt = 0; mt < 4; ++mt)
#pragma unroll
        for (int nb = 0; nb < 2; ++nb) acc[mt][nb] = f32x4{0.f, 0.f, 0.f, 0.f};

#pragma unroll
    for (int mt = 0; mt < 4; ++mt) {
        int link = lblk + mt * 16 + l15;
        bool ok = link < n_links;
        bf16x8 nv8 = zf, lsv8 = zf;
        if (ok) {
            int snd = senders[link];
            nv8 = *(const bf16x8*)(nsb16 + (size_t)snd * 32 + kg * 8);
            lsv8 = *(const bf16x8*)(lsb16 + (size_t)link * 32 + wv * 8);
        }
        float nf[8], lf[8];
#pragma unroll
        for (int j = 0; j < 8; ++j) {
            nf[j] = bf2f((unsigned short)nv8[j]);
            lf[j] = bf2f((unsigned short)lsv8[j]);
        }
#pragma unroll
        for (int kt = 0; kt < 8; ++kt) {
            bf16x8 aA;
#pragma unroll
            for (int jj = 0; jj < 8; ++jj) aA[jj] = (short)f2bf(lf[kt] * nf[jj]);
            acc[mt][0] = __builtin_amdgcn_mfma_f32_16x16x32_bf16(aA, Bf[kt][0], acc[mt][0], 0, 0, 0);
            acc[mt][1] = __builtin_amdgcn_mfma_f32_16x16x32_bf16(aA, Bf[kt][1], acc[mt][1], 0, 0, 0);
        }
        if (wv == 0) {
            acc[mt][0] = __builtin_amdgcn_mfma_f32_16x16x32_bf16(nv8, Bb[0], acc[mt][0], 0, 0, 0);
            acc[mt][1] = __builtin_amdgcn_mfma_f32_16x16x32_bf16(nv8, Bb[1], acc[mt][1], 0, 0, 0);
        }
    }
#pragma unroll
    for (int mt = 0; mt < 4; ++mt)
#pragma unroll
        for (int nb = 0; nb < 2; ++nb)
#pragma unroll
            for (int i = 0; i < 4; ++i)
                part[wv][(mt * 16 + kg * 4 + i) * 32 + nb * 16 + l15] = acc[mt][nb][i];
    __syncthreads();
    {
        int f = tid * 8;
        int link = lblk + (f >> 5);
        if (link < n_links) {
            float4 s0 = make_float4(0.f, 0.f, 0.f, 0.f), s1 = s0;
#pragma unroll
            for (int w = 0; w < 4; ++w) {
                const float4* p = (const float4*)(&part[w][f]);
                float4 a = p[0], b = p[1];
                s0.x += a.x; s0.y += a.y; s0.z += a.z; s0.w += a.w;
                s1.x += b.x; s1.y += b.y; s1.z += b.z; s1.w += b.w;
            }
            float4* dst = (float4*)(msg + (size_t)link * 32 + (f & 31));
            dst[0] = s0;
            dst[1] = s1;
        }
    }
}

// ---- node update: nsb16 = bf16(CSR-gather(msg) + ns_old @ wroot + broot) ----
extern "C" __global__ void __launch_bounds__(256, 2)
node_kernel(const float* __restrict__ msg, const int* __restrict__ csr_off,
            const int* __restrict__ csr_e, const float* __restrict__ nso,
            const float* __restrict__ wroot, const float* __restrict__ broot,
            unsigned short* __restrict__ nsb16, int n_nodes) {
    __shared__ float wr_l[1024];
    __shared__ float ns_s[8][32];
    int tid = threadIdx.x;
    for (int i = tid; i < 1024; i += 256) wr_l[i] = wroot[i];
    int ni = tid >> 5, o = tid & 31;
    int n = blockIdx.x * 8 + ni;
    if (n < n_nodes) ns_s[ni][o] = nso[(size_t)n * 32 + o];
    __syncthreads();
    if (n >= n_nodes) return;
    float acc = broot[o];
    {
        int k = csr_off[n], kend = csr_off[n + 1];
        for (; k + 2 <= kend; k += 2) {
            int e0 = csr_e[k], e1 = csr_e[k + 1];
            acc += msg[(size_t)e0 * 32 + o] + msg[(size_t)e1 * 32 + o];
        }
        if (k < kend) acc += msg[(size_t)csr_e[k] * 32 + o];
    }
#pragma unroll 8
    for (int k = 0; k < 32; ++k) acc = fmaf(ns_s[ni][k], wr_l[k * 32 + o], acc);
    nsb16[(size_t)n * 32 + o] = (unsigned short)f2bf(acc);
}

extern "C" void kernel_launch(void* const* d_in, const int* in_sizes, int n_in,
                              void* d_out, int out_size, void* d_ws, size_t ws_size,
                              hipStream_t stream) {
    const float* link_init = (const float*)d_in[0];
    const float* node_init = (const float*)d_in[1];
    const float* path_init = (const float*)d_in[2];
    const float* gru_wx = (const float*)d_in[3];
    const float* gru_wh = (const float*)d_in[4];
    const float* gru_b = (const float*)d_in[5];
    const float* e_w1 = (const float*)d_in[6];
    const float* e_b1 = (const float*)d_in[7];
    const float* e_w2 = (const float*)d_in[8];
    const float* e_b2 = (const float*)d_in[9];
    const float* ecc_wk = (const float*)d_in[10];
    const float* ecc_bk = (const float*)d_in[11];
    const float* ecc_wroot = (const float*)d_in[12];
    const float* ecc_broot = (const float*)d_in[13];
    const float* r_w1 = (const float*)d_in[14];
    const float* r_b1 = (const float*)d_in[15];
    const float* r_w2 = (const float*)d_in[16];
    const float* r_b2 = (const float*)d_in[17];
    const float* f_w = (const float*)d_in[18];
    const float* f_b = (const float*)d_in[19];
    const int* p2l = (const int*)d_in[20];
    const int* sseq = (const int*)d_in[21];
    const int* l2p = (const int*)d_in[22];
    const int* n2p = (const int*)d_in[23];
    const int* l2n = (const int*)d_in[24];
    const int* senders = (const int*)d_in[25];
    const int* receivers = (const int*)d_in[26];

    const int nl = in_sizes[0];
    const int nn = in_sizes[1];
    const int np = in_sizes[2] / 2;
    const int E = in_sizes[20];

    char* base = (char*)d_ws;
    size_t off = 0;
    auto give = [&](size_t nbytes) -> void* {
        void* p = base + off;
        off += (nbytes + 255) & ~(size_t)255;
        return p;
    };
    float* ls0 = (float*)give((size_t)nl * 32 * 4);
    float* ns0 = (float*)give((size_t)nn * 32 * 4);
    float* ps = (float*)give((size_t)np * 64 * 4);
    float* We = (float*)give(4096 * 4);
    float* be = (float*)give(32 * 4);
    unsigned int* gln = (unsigned int*)give((size_t)np * N_ML * 4);
    unsigned short* lsb16 = (unsigned short*)give((size_t)nl * 32 * 2);
    unsigned short* nsb16 = (unsigned short*)give((size_t)nn * 32 * 2);
    unsigned short* wkbf = (unsigned short*)give(32768 * 2);
    unsigned short* bkbf = (unsigned short*)give(1024 * 2);
    float* msg = (float*)give((size_t)nl * 32 * 4);
    int* csr_off = (int*)give((size_t)(nn + 1) * 4);
    int* csr_e = (int*)give((size_t)nl * 4);
    // contiguous zero region: lensb | cntn | curn | m  (single memset)
    char* zbase = base + off;
    int* lensb = (int*)give((size_t)np * 4);
    int* cntn = (int*)give((size_t)nn * 4);
    int* curn = (int*)give((size_t)nn * 4);
    float* m = (float*)give((size_t)nl * 64 * 4);
    size_t zlen = (char*)(m + (size_t)nl * 64) - zbase;

    hipMemsetAsync(zbase, 0, zlen, stream);
    hipMemsetAsync(gln, 0xFF, (size_t)np * N_ML * 4, stream);

    // merged setup dispatch
    const int nb_init = (((nl > nn ? nl : nn) > np ? (nl > nn ? nl : nn) : np) + 255) / 256;
    const int nb_idx = (E + 255) / 256;
    const int nb_cnt = (nl + 255) / 256;
    const int o_ecc = 16;
    const int o_init = o_ecc + 128;
    const int o_idx = o_init + nb_init;
    const int o_cnt = o_idx + nb_idx;
    const int nb_tot = o_cnt + nb_cnt;
    setup_kernel<<<nb_tot, 256, 0, stream>>>(
        e_w1, e_b1, e_w2, e_b2, We, be, ecc_wk, ecc_bk, wkbf, bkbf,
        link_init, node_init, path_init, ls0, ns0, ps, lsb16, nsb16,
        p2l, sseq, l2p, n2p, gln, lensb, receivers, cntn,
        nl, nn, np, E, o_ecc, o_init, o_idx, o_cnt);
    scan_kernel<<<1, 1024, 0, stream>>>(cntn, csr_off, nn);
    scatter_kernel<<<(nl + 255) / 256, 256, 0, stream>>>(receivers, csr_off, curn, csr_e, nl);

    const int gblocks = (np + 31) / 32;
    // iter 1: full update
    gru_kernel<false><<<gblocks, 256, 0, stream>>>(
        lsb16, nsb16, ps, m, gln, lensb, gru_wx, gru_wh, gru_b, np,
        r_w1, r_b1, r_w2, r_b2, f_w, f_b, (float*)d_out);
    edge_kernel<<<(nl + 7) / 8, 256, 0, stream>>>(ns0, ls0, m, We, be, l2n, lsb16, nl);
    ecc_kernel<<<(nl + 63) / 64, 256, 0, stream>>>(lsb16, nsb16, wkbf, bkbf, senders, msg, nl);
    node_kernel<<<(nn + 7) / 8, 256, 0, stream>>>(msg, csr_off, csr_e, ns0, ecc_wroot,
                                                  ecc_broot, nsb16, nn);
    // iter 2: only path_state matters -> gru with fused readout
    gru_kernel<true><<<gblocks, 256, 0, stream>>>(
        lsb16, nsb16, ps, m, gln, lensb, gru_wx, gru_wh, gru_b, np,
        r_w1, r_b1, r_w2, r_b2, f_w, f_b, (float*)d_out);
}

// Round 14
// 396.364 us; speedup vs baseline: 3.6739x; 1.9320x over previous
//
#include <hip/hip_runtime.h>
#include <cstdint>

#define N_ML 8   // MAX_LEN
#define HSTR 72  // h_lds row stride in bf16 elements

typedef __attribute__((ext_vector_type(8))) short bf16x8;
typedef __attribute__((ext_vector_type(4))) float f32x4;

__device__ __forceinline__ float fsigmoid(float x) { return 1.f / (1.f + __expf(-x)); }
// tanh(x) = 2*sigmoid(2x) - 1  (exact, saturates correctly at +/-inf)
__device__ __forceinline__ float ftanh_(float x) {
    return fmaf(2.f, 1.f / (1.f + __expf(-2.f * x)), -1.f);
}
__device__ __forceinline__ float fselu(float x) {
    const float sc = 1.0507009873554805f, al = 1.6732632423543772f;
    return x > 0.f ? sc * x : sc * al * (__expf(x) - 1.f);
}
// f32 -> bf16 RTNE
__device__ __forceinline__ unsigned int f2bf(float f) {
    union { float f; unsigned int u; } v;
    v.f = f;
    unsigned int u = v.u;
    return (u + 0x7FFFu + ((u >> 16) & 1u)) >> 16;
}
__device__ __forceinline__ float bf2f(unsigned short u16) {
    union { unsigned int u; float f; } v;
    v.u = ((unsigned int)u16) << 16;
    return v.f;
}

// LDS-only barrier: waits DS ops, NOT vmcnt (no drain of prefetch/atomics).
__device__ __forceinline__ void barrier_lds_only() {
    asm volatile("s_waitcnt lgkmcnt(0)" ::: "memory");
    __builtin_amdgcn_s_barrier();
    asm volatile("" ::: "memory");
}

// ---- merged setup: prep_we | prep_ecc | init_states | build_idx | count ----
__global__ void __launch_bounds__(256)
setup_kernel(const float* __restrict__ ew1, const float* __restrict__ eb1,
             const float* __restrict__ ew2, const float* __restrict__ eb2,
             float* __restrict__ We, float* __restrict__ be,
             const float* __restrict__ wk, const float* __restrict__ bk,
             unsigned short* __restrict__ wkbf, unsigned short* __restrict__ bkbf,
             const float* __restrict__ li, const float* __restrict__ ni,
             const float* __restrict__ pi, float* __restrict__ ls,
             float* __restrict__ ns, float* __restrict__ ps,
             unsigned short* __restrict__ lsb16, unsigned short* __restrict__ nsb16,
             const int* __restrict__ paths, const int* __restrict__ seqs,
             const int* __restrict__ l2p, const int* __restrict__ n2p,
             unsigned int* __restrict__ gln, int* __restrict__ lens,
             const int* __restrict__ rcv, int* __restrict__ cnt,
             int n_links, int n_nodes, int n_paths, int E,
             int o_ecc, int o_init, int o_idx, int o_cnt) {
    const int b = blockIdx.x;
    const int tid = threadIdx.x;
    if (b < o_ecc) {
        int t = b * 256 + tid;
        if (t < 4096) {
            int k = t >> 5, j = t & 31;
            float a = 0.f;
            for (int i = 0; i < 32; ++i) a = fmaf(ew1[k * 32 + i], ew2[i * 32 + j], a);
            We[t] = a;
        }
        if (b == 0 && tid < 32) {
            int j = tid;
            float a = eb2[j];
            for (int i = 0; i < 32; ++i) a = fmaf(eb1[i], ew2[i * 32 + j], a);
            be[j] = a;
        }
    } else if (b < o_init) {
        int t = (b - o_ecc) * 256 + tid;
        if (t < 32768) {
            int o = t >> 10, q = t & 1023;
            int j = q >> 5, i = q & 31;
            wkbf[t] = (unsigned short)f2bf(wk[j * 1024 + i * 32 + o]);
        }
        if (t < 1024) {
            int o = t >> 5, i = t & 31;
            bkbf[t] = (unsigned short)f2bf(bk[i * 32 + o]);
        }
    } else if (b < o_idx) {
        int t = (b - o_init) * 256 + tid;
        float4 z = make_float4(0.f, 0.f, 0.f, 0.f);
        if (t < n_links) {
            float v = li[t];
            float4* r = (float4*)(ls + (size_t)t * 32);
            r[0] = make_float4(v, 0.f, 0.f, 0.f);
#pragma unroll
            for (int i = 1; i < 8; ++i) r[i] = z;
            uint4* bb = (uint4*)(lsb16 + (size_t)t * 32);
            uint4 zb = make_uint4(0, 0, 0, 0);
            bb[0] = make_uint4(f2bf(v), 0, 0, 0);
            bb[1] = zb; bb[2] = zb; bb[3] = zb;
        }
        if (t < n_nodes) {
            float v = ni[t];
            float4* r = (float4*)(ns + (size_t)t * 32);
            r[0] = make_float4(v, 0.f, 0.f, 0.f);
#pragma unroll
            for (int i = 1; i < 8; ++i) r[i] = z;
            uint4* bb = (uint4*)(nsb16 + (size_t)t * 32);
            uint4 zb = make_uint4(0, 0, 0, 0);
            bb[0] = make_uint4(f2bf(v), 0, 0, 0);
            bb[1] = zb; bb[2] = zb; bb[3] = zb;
        }
        if (t < n_paths) {
            float4* r = (float4*)(ps + (size_t)t * 64);
            r[0] = make_float4(pi[t], pi[n_paths + t], 0.f, 0.f);
#pragma unroll
            for (int i = 1; i < 16; ++i) r[i] = z;
        }
    } else if (b < o_cnt) {
        int e = (b - o_idx) * 256 + tid;
        if (e < E) {
            int p = paths[e], s = seqs[e];
            gln[(size_t)p * N_ML + s] =
                ((unsigned int)l2p[e] & 0xFFFFu) | ((unsigned int)n2p[e] << 16);
            atomicAdd(&lens[p], 1);
        }
    } else {
        int e = (b - o_cnt) * 256 + tid;
        if (e < n_links) atomicAdd(&cnt[rcv[e]], 1);
    }
}

__global__ void __launch_bounds__(1024, 1)
scan_kernel(const int* __restrict__ cnt, int* __restrict__ off, int n) {
    __shared__ int sd[1024];
    int tid = threadIdx.x;
    int chunk = (n + 1023) >> 10;
    int base = tid * chunk;
    int s = 0;
    for (int i = 0; i < chunk; ++i) {
        int idx = base + i;
        if (idx < n) s += cnt[idx];
    }
    sd[tid] = s;
    __syncthreads();
    for (int o = 1; o < 1024; o <<= 1) {
        int v = (tid >= o) ? sd[tid - o] : 0;
        __syncthreads();
        sd[tid] += v;
        __syncthreads();
    }
    int run = sd[tid] - s;  // exclusive
    for (int i = 0; i < chunk; ++i) {
        int idx = base + i;
        if (idx < n) {
            off[idx] = run;
            run += cnt[idx];
        }
    }
    if (tid == 1023) off[n] = sd[1023];
}

__global__ void scatter_kernel(const int* __restrict__ rcv, const int* __restrict__ off,
                               int* __restrict__ cur, int* __restrict__ csr_e, int E) {
    int e = blockIdx.x * 256 + threadIdx.x;
    if (e < E) {
        int l = rcv[e];
        int p = off[l] + atomicAdd(&cur[l], 1);
        csr_e[p] = e;
    }
}

// ---- GRU scan via MFMA; 256 thr / 4 waves / 32 paths per block ----
// min_waves_per_EU MUST be <= 2 on gfx950: empirical VGPR cap = 256/min_waves
// (R11 (256,8)->32 VGPR, R12 (256,4)->64 VGPR: both remat weights from
// global, FETCH 14MB->0.5-0.9GB). (*,2) -> cap 128, kernel needs ~92.
template <bool LAST>
__global__ void __launch_bounds__(256, 2)
gru_kernel(const unsigned short* __restrict__ lsb16, const unsigned short* __restrict__ nsb16,
           float* __restrict__ ps, float* __restrict__ m,
           const unsigned int* __restrict__ gln, const int* __restrict__ lens,
           const float* __restrict__ wx, const float* __restrict__ wh,
           const float* __restrict__ gb, int n_paths,
           const float* __restrict__ r_w1, const float* __restrict__ r_b1,
           const float* __restrict__ r_w2, const float* __restrict__ r_b2,
           const float* __restrict__ f_w, const float* __restrict__ f_b,
           float* __restrict__ out) {
    __shared__ unsigned short h_lds[2][32 * HSTR];  // 2 x 4.5KB
    __shared__ unsigned int gln_lds[N_ML * 32];     // 1KB  [t][row]
    __shared__ float h32[32 * 66];                  // 8.25KB final f32 h (LAST)
    __shared__ float r1_s[8][33];                   // 1KB readout stage (LAST)
    const int tid = threadIdx.x;
    const int lane = tid & 63;
    const int nw = tid >> 6;  // dim-block 0..3 (one wave each)
    const int l15 = lane & 15;
    const int kg = lane >> 4;  // 0..3
    const int pblk = blockIdx.x * 32;
    const int d = nw * 16 + l15;  // output dim 0..63

    {
        int st = tid >> 5, sr = tid & 31;  // 8 t-slots x 32 rows
        int pc = pblk + sr;
        gln_lds[st * 32 + sr] = (pc < n_paths) ? gln[(size_t)pc * N_ML + st] : 0xFFFFFFFFu;
    }

    bf16x8 Bz[4], Br[4], Bcx[2], Bch[2];
#pragma unroll
    for (int kt = 0; kt < 4; ++kt) {
        int kb = kt * 32 + kg * 8;
        const float* W = (kb < 64) ? (wx + (size_t)kb * 192) : (wh + (size_t)(kb - 64) * 192);
        bf16x8 vz, vr, vc;
#pragma unroll
        for (int j = 0; j < 8; ++j) {
            vz[j] = (short)f2bf(W[j * 192 + d]);
            vr[j] = (short)f2bf(W[j * 192 + 64 + d]);
            vc[j] = (short)f2bf(W[j * 192 + 128 + d]);
        }
        Bz[kt] = vz;
        Br[kt] = vr;
        if (kt < 2) Bcx[kt] = vc; else Bch[kt - 2] = vc;
    }
    const float bias_z = gb[d] + gb[192 + d];
    const float bias_r = gb[64 + d] + gb[192 + 64 + d];
    const float bias_xh = gb[128 + d];
    const float bias_hh = gb[192 + 128 + d];

    f32x4 hv[2];
    unsigned int plenp[2];
#pragma unroll
    for (int mt = 0; mt < 2; ++mt) {
        unsigned int pk = 0;
#pragma unroll
        for (int i = 0; i < 4; ++i) {
            int r = mt * 16 + kg * 4 + i;
            int pc = pblk + r;
            bool v = pc < n_paths;
            float h0 = v ? ps[(size_t)pc * 64 + d] : 0.f;
            hv[mt][i] = h0;
            pk |= (unsigned int)(v ? lens[pc] : 0) << (8 * i);
            h_lds[0][r * HSTR + d] = (unsigned short)f2bf(h0);
        }
        plenp[mt] = pk;
    }
    barrier_lds_only();

    bf16x8 ax0[2][2], ax1[2][2];  // [buf][mt]
    const bf16x8 zf = bf16x8{0, 0, 0, 0, 0, 0, 0, 0};

    auto loadx = [&](int t, int buf) {
#pragma unroll
        for (int mt = 0; mt < 2; ++mt) {
            int row = mt * 16 + l15;
            unsigned int g = gln_lds[t * 32 + row];
            ax0[buf][mt] = zf;
            ax1[buf][mt] = zf;
            if (g != 0xFFFFFFFFu) {
                int lk = (int)(g & 0xFFFFu);
                int nd = (int)(g >> 16);
                ax0[buf][mt] = *(const bf16x8*)(lsb16 + (size_t)lk * 32 + kg * 8);
                ax1[buf][mt] = *(const bf16x8*)(nsb16 + (size_t)nd * 32 + kg * 8);
            }
        }
    };
    loadx(0, 0);

#pragma unroll
    for (int t = 0; t < N_ML; ++t) {
        const int cb = t & 1, nb = cb ^ 1;
        if (t < N_ML - 1) loadx(t + 1, nb);
        bf16x8 ah0[2], ah1[2];
#pragma unroll
        for (int mt = 0; mt < 2; ++mt) {
            int row = mt * 16 + l15;
            ah0[mt] = *(const bf16x8*)(&h_lds[cb][row * HSTR + kg * 8]);
            ah1[mt] = *(const bf16x8*)(&h_lds[cb][row * HSTR + 32 + kg * 8]);
        }
        f32x4 accZ[2], accR[2], accXH[2], accHH[2];
#pragma unroll
        for (int mt = 0; mt < 2; ++mt) {
            accZ[mt] = f32x4{bias_z, bias_z, bias_z, bias_z};
            accR[mt] = f32x4{bias_r, bias_r, bias_r, bias_r};
            accXH[mt] = f32x4{bias_xh, bias_xh, bias_xh, bias_xh};
            accHH[mt] = f32x4{bias_hh, bias_hh, bias_hh, bias_hh};
            accZ[mt] = __builtin_amdgcn_mfma_f32_16x16x32_bf16(ax0[cb][mt], Bz[0], accZ[mt], 0, 0, 0);
            accZ[mt] = __builtin_amdgcn_mfma_f32_16x16x32_bf16(ax1[cb][mt], Bz[1], accZ[mt], 0, 0, 0);
            accZ[mt] = __builtin_amdgcn_mfma_f32_16x16x32_bf16(ah0[mt], Bz[2], accZ[mt], 0, 0, 0);
            accZ[mt] = __builtin_amdgcn_mfma_f32_16x16x32_bf16(ah1[mt], Bz[3], accZ[mt], 0, 0, 0);
            accR[mt] = __builtin_amdgcn_mfma_f32_16x16x32_bf16(ax0[cb][mt], Br[0], accR[mt], 0, 0, 0);
            accR[mt] = __builtin_amdgcn_mfma_f32_16x16x32_bf16(ax1[cb][mt], Br[1], accR[mt], 0, 0, 0);
            accR[mt] = __builtin_amdgcn_mfma_f32_16x16x32_bf16(ah0[mt], Br[2], accR[mt], 0, 0, 0);
            accR[mt] = __builtin_amdgcn_mfma_f32_16x16x32_bf16(ah1[mt], Br[3], accR[mt], 0, 0, 0);
            accXH[mt] = __builtin_amdgcn_mfma_f32_16x16x32_bf16(ax0[cb][mt], Bcx[0], accXH[mt], 0, 0, 0);
            accXH[mt] = __builtin_amdgcn_mfma_f32_16x16x32_bf16(ax1[cb][mt], Bcx[1], accXH[mt], 0, 0, 0);
            accHH[mt] = __builtin_amdgcn_mfma_f32_16x16x32_bf16(ah0[mt], Bch[0], accHH[mt], 0, 0, 0);
            accHH[mt] = __builtin_amdgcn_mfma_f32_16x16x32_bf16(ah1[mt], Bch[1], accHH[mt], 0, 0, 0);
        }
        float ov[2][4];
#pragma unroll
        for (int mt = 0; mt < 2; ++mt) {
#pragma unroll
            for (int i = 0; i < 4; ++i) {
                int r = mt * 16 + kg * 4 + i;
                float z = fsigmoid(accZ[mt][i]);
                float rr = fsigmoid(accR[mt][i]);
                float c = ftanh_(accXH[mt][i] + rr * accHH[mt][i]);
                float hn = z * hv[mt][i] + (1.f - z) * c;
                bool msk = ((plenp[mt] >> (8 * i)) & 0xFFu) > (unsigned int)t;
                float nh = msk ? hn : hv[mt][i];
                hv[mt][i] = nh;
                h_lds[nb][r * HSTR + d] = (unsigned short)f2bf(nh);
                ov[mt][i] = msk ? hn : 0.f;
            }
        }
        barrier_lds_only();  // LDS visibility only; vmcnt stays in flight
        if constexpr (!LAST) {
#pragma unroll
            for (int mt = 0; mt < 2; ++mt) {
#pragma unroll
                for (int i = 0; i < 4; ++i) {
                    int r = mt * 16 + kg * 4 + i;
                    unsigned int g = gln_lds[t * 32 + r];
                    if (g != 0xFFFFFFFFu)
                        atomicAdd(&m[(size_t)(g & 0xFFFFu) * 64 + d], ov[mt][i]);
                }
            }
        }
    }
    if constexpr (!LAST) {
#pragma unroll
        for (int mt = 0; mt < 2; ++mt) {
#pragma unroll
            for (int i = 0; i < 4; ++i) {
                int pc = pblk + mt * 16 + kg * 4 + i;
                if (pc < n_paths) ps[(size_t)pc * 64 + d] = hv[mt][i];
            }
        }
    } else {
        // fused readout: stage f32 h, then selu MLP + head per path
#pragma unroll
        for (int mt = 0; mt < 2; ++mt)
#pragma unroll
            for (int i = 0; i < 4; ++i) {
                int r = mt * 16 + kg * 4 + i;
                h32[r * 66 + d] = hv[mt][i];
            }
        barrier_lds_only();
        const int j = tid & 31, grp = tid >> 5;  // 8 groups of 32 lanes
#pragma unroll
        for (int pass = 0; pass < 4; ++pass) {
            int prow = pass * 8 + grp;
            int p = pblk + prow;
            float a = r_b1[j];
#pragma unroll 16
            for (int k = 0; k < 64; ++k) a = fmaf(h32[prow * 66 + k], r_w1[k * 32 + j], a);
            r1_s[grp][j] = fselu(a);
            barrier_lds_only();
            float bacc = r_b2[j];
#pragma unroll 8
            for (int k = 0; k < 32; ++k) bacc = fmaf(r1_s[grp][k], r_w2[k * 32 + j], bacc);
            float part = fselu(bacc) * f_w[j] + h32[prow * 66 + j] * f_w[32 + j] +
                         h32[prow * 66 + 32 + j] * f_w[64 + j];
#pragma unroll
            for (int o = 16; o > 0; o >>= 1) part += __shfl_down(part, o, 32);
            if (j == 0 && p < n_paths) out[p] = part + f_b[0];
            barrier_lds_only();
        }
    }
}

// ---- edge MLP (pre-folded): lsb16 = bf16(con @ We + be) ----
extern "C" __global__ void __launch_bounds__(256, 2)
edge_kernel(const float* __restrict__ ns, const float* __restrict__ lso,
            const float* __restrict__ m, const float* __restrict__ We,
            const float* __restrict__ be, const int* __restrict__ l2n,
            unsigned short* __restrict__ lsb16, int n_links) {
    __shared__ float We_l[4096];
    __shared__ float be_l[32];
    __shared__ float con_l[8][128];
    int tid = threadIdx.x;
    for (int i = tid; i < 4096; i += 256) We_l[i] = We[i];
    if (tid < 32) be_l[tid] = be[tid];
    int li = tid >> 5, o = tid & 31;
    int l = blockIdx.x * 8 + li;
    if (l < n_links) {
        con_l[li][o] = ns[(size_t)l2n[l] * 32 + o];
        con_l[li][32 + o] = lso[(size_t)l * 32 + o];
        con_l[li][64 + o] = m[(size_t)l * 64 + o];
        con_l[li][96 + o] = m[(size_t)l * 64 + 32 + o];
    }
    __syncthreads();
    if (l >= n_links) return;
    float acc = be_l[o];
#pragma unroll 8
    for (int k = 0; k < 128; ++k) acc = fmaf(con_l[li][k], We_l[k * 32 + o], acc);
    lsb16[(size_t)l * 32 + o] = (unsigned short)f2bf(acc);
}

// ---- ECCConv via MFMA bilinear form: msg = P @ wk_view + n @ bk_view ----
extern "C" __global__ void __launch_bounds__(256, 2)
ecc_kernel(const unsigned short* __restrict__ lsb16, const unsigned short* __restrict__ nsb16,
           const unsigned short* __restrict__ wkbf, const unsigned short* __restrict__ bkbf,
           const int* __restrict__ senders, float* __restrict__ msg, int n_links) {
    __shared__ float part[4][64 * 32];  // [wave][row][o] f32, 32KB
    const int tid = threadIdx.x;
    const int lane = tid & 63;
    const int wv = tid >> 6;   // K-slice 0..3
    const int l15 = lane & 15;
    const int kg = lane >> 4;  // 0..3
    const int lblk = blockIdx.x * 64;
    const bf16x8 zf = bf16x8{0, 0, 0, 0, 0, 0, 0, 0};

    bf16x8 Bf[8][2], Bb[2];
#pragma unroll
    for (int kt = 0; kt < 8; ++kt) {
#pragma unroll
        for (int nb = 0; nb < 2; ++nb) {
            int o = nb * 16 + l15;
            Bf[kt][nb] = *(const bf16x8*)(wkbf + (size_t)o * 1024 + wv * 256 + kt * 32 + kg * 8);
        }
    }
#pragma unroll
    for (int nb = 0; nb < 2; ++nb) {
        int o = nb * 16 + l15;
        Bb[nb] = *(const bf16x8*)(bkbf + (size_t)o * 32 + kg * 8);
    }

    f32x4 acc[4][2];
#pragma unroll
    for (int mt = 0; mt < 4; ++mt)
#pragma unroll
        for (int nb = 0; nb < 2; ++nb) acc[mt][nb] = f32x4{0.f, 0.f, 0.f, 0.f};

#pragma unroll
    for (int mt = 0; mt < 4; ++mt) {
        int link = lblk + mt * 16 + l15;
        bool ok = link < n_links;
        bf16x8 nv8 = zf, lsv8 = zf;
        if (ok) {
            int snd = senders[link];
            nv8 = *(const bf16x8*)(nsb16 + (size_t)snd * 32 + kg * 8);
            lsv8 = *(const bf16x8*)(lsb16 + (size_t)link * 32 + wv * 8);
        }
        float nf[8], lf[8];
#pragma unroll
        for (int j = 0; j < 8; ++j) {
            nf[j] = bf2f((unsigned short)nv8[j]);
            lf[j] = bf2f((unsigned short)lsv8[j]);
        }
#pragma unroll
        for (int kt = 0; kt < 8; ++kt) {
            bf16x8 aA;
#pragma unroll
            for (int jj = 0; jj < 8; ++jj) aA[jj] = (short)f2bf(lf[kt] * nf[jj]);
            acc[mt][0] = __builtin_amdgcn_mfma_f32_16x16x32_bf16(aA, Bf[kt][0], acc[mt][0], 0, 0, 0);
            acc[mt][1] = __builtin_amdgcn_mfma_f32_16x16x32_bf16(aA, Bf[kt][1], acc[mt][1], 0, 0, 0);
        }
        if (wv == 0) {
            acc[mt][0] = __builtin_amdgcn_mfma_f32_16x16x32_bf16(nv8, Bb[0], acc[mt][0], 0, 0, 0);
            acc[mt][1] = __builtin_amdgcn_mfma_f32_16x16x32_bf16(nv8, Bb[1], acc[mt][1], 0, 0, 0);
        }
    }
#pragma unroll
    for (int mt = 0; mt < 4; ++mt)
#pragma unroll
        for (int nb = 0; nb < 2; ++nb)
#pragma unroll
            for (int i = 0; i < 4; ++i)
                part[wv][(mt * 16 + kg * 4 + i) * 32 + nb * 16 + l15] = acc[mt][nb][i];
    __syncthreads();
    {
        int f = tid * 8;
        int link = lblk + (f >> 5);
        if (link < n_links) {
            float4 s0 = make_float4(0.f, 0.f, 0.f, 0.f), s1 = s0;
#pragma unroll
            for (int w = 0; w < 4; ++w) {
                const float4* p = (const float4*)(&part[w][f]);
                float4 a = p[0], b = p[1];
                s0.x += a.x; s0.y += a.y; s0.z += a.z; s0.w += a.w;
                s1.x += b.x; s1.y += b.y; s1.z += b.z; s1.w += b.w;
            }
            float4* dst = (float4*)(msg + (size_t)link * 32 + (f & 31));
            dst[0] = s0;
            dst[1] = s1;
        }
    }
}

// ---- node update: nsb16 = bf16(CSR-gather(msg) + ns_old @ wroot + broot) ----
extern "C" __global__ void __launch_bounds__(256, 2)
node_kernel(const float* __restrict__ msg, const int* __restrict__ csr_off,
            const int* __restrict__ csr_e, const float* __restrict__ nso,
            const float* __restrict__ wroot, const float* __restrict__ broot,
            unsigned short* __restrict__ nsb16, int n_nodes) {
    __shared__ float wr_l[1024];
    __shared__ float ns_s[8][32];
    int tid = threadIdx.x;
    for (int i = tid; i < 1024; i += 256) wr_l[i] = wroot[i];
    int ni = tid >> 5, o = tid & 31;
    int n = blockIdx.x * 8 + ni;
    if (n < n_nodes) ns_s[ni][o] = nso[(size_t)n * 32 + o];
    __syncthreads();
    if (n >= n_nodes) return;
    float acc = broot[o];
    {
        int k = csr_off[n], kend = csr_off[n + 1];
        for (; k + 2 <= kend; k += 2) {
            int e0 = csr_e[k], e1 = csr_e[k + 1];
            acc += msg[(size_t)e0 * 32 + o] + msg[(size_t)e1 * 32 + o];
        }
        if (k < kend) acc += msg[(size_t)csr_e[k] * 32 + o];
    }
#pragma unroll 8
    for (int k = 0; k < 32; ++k) acc = fmaf(ns_s[ni][k], wr_l[k * 32 + o], acc);
    nsb16[(size_t)n * 32 + o] = (unsigned short)f2bf(acc);
}

extern "C" void kernel_launch(void* const* d_in, const int* in_sizes, int n_in,
                              void* d_out, int out_size, void* d_ws, size_t ws_size,
                              hipStream_t stream) {
    const float* link_init = (const float*)d_in[0];
    const float* node_init = (const float*)d_in[1];
    const float* path_init = (const float*)d_in[2];
    const float* gru_wx = (const float*)d_in[3];
    const float* gru_wh = (const float*)d_in[4];
    const float* gru_b = (const float*)d_in[5];
    const float* e_w1 = (const float*)d_in[6];
    const float* e_b1 = (const float*)d_in[7];
    const float* e_w2 = (const float*)d_in[8];
    const float* e_b2 = (const float*)d_in[9];
    const float* ecc_wk = (const float*)d_in[10];
    const float* ecc_bk = (const float*)d_in[11];
    const float* ecc_wroot = (const float*)d_in[12];
    const float* ecc_broot = (const float*)d_in[13];
    const float* r_w1 = (const float*)d_in[14];
    const float* r_b1 = (const float*)d_in[15];
    const float* r_w2 = (const float*)d_in[16];
    const float* r_b2 = (const float*)d_in[17];
    const float* f_w = (const float*)d_in[18];
    const float* f_b = (const float*)d_in[19];
    const int* p2l = (const int*)d_in[20];
    const int* sseq = (const int*)d_in[21];
    const int* l2p = (const int*)d_in[22];
    const int* n2p = (const int*)d_in[23];
    const int* l2n = (const int*)d_in[24];
    const int* senders = (const int*)d_in[25];
    const int* receivers = (const int*)d_in[26];

    const int nl = in_sizes[0];
    const int nn = in_sizes[1];
    const int np = in_sizes[2] / 2;
    const int E = in_sizes[20];

    char* base = (char*)d_ws;
    size_t off = 0;
    auto give = [&](size_t nbytes) -> void* {
        void* p = base + off;
        off += (nbytes + 255) & ~(size_t)255;
        return p;
    };
    float* ls0 = (float*)give((size_t)nl * 32 * 4);
    float* ns0 = (float*)give((size_t)nn * 32 * 4);
    float* ps = (float*)give((size_t)np * 64 * 4);
    float* We = (float*)give(4096 * 4);
    float* be = (float*)give(32 * 4);
    unsigned int* gln = (unsigned int*)give((size_t)np * N_ML * 4);
    unsigned short* lsb16 = (unsigned short*)give((size_t)nl * 32 * 2);
    unsigned short* nsb16 = (unsigned short*)give((size_t)nn * 32 * 2);
    unsigned short* wkbf = (unsigned short*)give(32768 * 2);
    unsigned short* bkbf = (unsigned short*)give(1024 * 2);
    float* msg = (float*)give((size_t)nl * 32 * 4);
    int* csr_off = (int*)give((size_t)(nn + 1) * 4);
    int* csr_e = (int*)give((size_t)nl * 4);
    // contiguous zero region: lensb | cntn | curn | m  (single memset)
    char* zbase = base + off;
    int* lensb = (int*)give((size_t)np * 4);
    int* cntn = (int*)give((size_t)nn * 4);
    int* curn = (int*)give((size_t)nn * 4);
    float* m = (float*)give((size_t)nl * 64 * 4);
    size_t zlen = (char*)(m + (size_t)nl * 64) - zbase;

    hipMemsetAsync(zbase, 0, zlen, stream);
    hipMemsetAsync(gln, 0xFF, (size_t)np * N_ML * 4, stream);

    // merged setup dispatch
    const int nb_init = (((nl > nn ? nl : nn) > np ? (nl > nn ? nl : nn) : np) + 255) / 256;
    const int nb_idx = (E + 255) / 256;
    const int nb_cnt = (nl + 255) / 256;
    const int o_ecc = 16;
    const int o_init = o_ecc + 128;
    const int o_idx = o_init + nb_init;
    const int o_cnt = o_idx + nb_idx;
    const int nb_tot = o_cnt + nb_cnt;
    setup_kernel<<<nb_tot, 256, 0, stream>>>(
        e_w1, e_b1, e_w2, e_b2, We, be, ecc_wk, ecc_bk, wkbf, bkbf,
        link_init, node_init, path_init, ls0, ns0, ps, lsb16, nsb16,
        p2l, sseq, l2p, n2p, gln, lensb, receivers, cntn,
        nl, nn, np, E, o_ecc, o_init, o_idx, o_cnt);
    scan_kernel<<<1, 1024, 0, stream>>>(cntn, csr_off, nn);
    scatter_kernel<<<(nl + 255) / 256, 256, 0, stream>>>(receivers, csr_off, curn, csr_e, nl);

    const int gblocks = (np + 31) / 32;
    // iter 1: full update
    gru_kernel<false><<<gblocks, 256, 0, stream>>>(
        lsb16, nsb16, ps, m, gln, lensb, gru_wx, gru_wh, gru_b, np,
        r_w1, r_b1, r_w2, r_b2, f_w, f_b, (float*)d_out);
    edge_kernel<<<(nl + 7) / 8, 256, 0, stream>>>(ns0, ls0, m, We, be, l2n, lsb16, nl);
    ecc_kernel<<<(nl + 63) / 64, 256, 0, stream>>>(lsb16, nsb16, wkbf, bkbf, senders, msg, nl);
    node_kernel<<<(nn + 7) / 8, 256, 0, stream>>>(msg, csr_off, csr_e, ns0, ecc_wroot,
                                                  ecc_broot, nsb16, nn);
    // iter 2: only path_state matters -> gru with fused readout
    gru_kernel<true><<<gblocks, 256, 0, stream>>>(
        lsb16, nsb16, ps, m, gln, lensb, gru_wx, gru_wh, gru_b, np,
        r_w1, r_b1, r_w2, r_b2, f_w, f_b, (float*)d_out);
}